// Round 4
// baseline (76.701 us; speedup 1.0000x reference)
//
#include <hip/hip_runtime.h>
#include <math.h>

#define KNN 8
#define CF 16
#define SRS 128
#define NRAYS 4096
#define TPB 512   // 4 lanes per sample, 128 samples per ray

__global__ __launch_bounds__(TPB) void pvr_fused_kernel(
    const float* __restrict__ points_feat,   // [N_PTS, 16]
    const int*   __restrict__ indices,       // [N, 8]
    const float* __restrict__ dists,         // [N, 8]
    const float* __restrict__ w_rgb,         // [16, 3]
    const float* __restrict__ w_sigma,       // [16, 1]
    const float* __restrict__ delta,         // [R, SR]
    const float* __restrict__ z_vals,        // [R, SR]
    float* __restrict__ out)                 // [R, 5]
{
    const int ray = blockIdx.x;
    const int t   = threadIdx.x;
    const int s   = t >> 2;                    // sample within ray (0..127)
    const int j   = t & 3;                     // chunk id within row (0..3)
    const long long n = (long long)ray * SRS + s;

    __shared__ float s_wrgb[CF * 3];
    __shared__ float s_wsig[CF];
    __shared__ float s_sig[SRS];
    __shared__ float s_rgbv[3][SRS];
    __shared__ float s_wavetot;
    __shared__ float s_red[2][5];

    if (t < CF * 3)            s_wrgb[t] = w_rgb[t];
    else if (t < CF * 3 + CF)  s_wsig[t - CF * 3] = w_sigma[t - CF * 3];

    // ---- lane j owns neighbor pair j: coalesced int2/float2 loads ----
    const int2   i2 = ((const int2*)indices)[n * 4 + j];
    const float2 d2 = ((const float2*)dists)[n * 4 + j];

    float w0 = 1.0f / (d2.x + 1e-7f);
    float w1 = 1.0f / (d2.y + 1e-7f);
    float wsum = w0 + w1;
    wsum += __shfl_xor(wsum, 1);
    wsum += __shfl_xor(wsum, 2);
    const float winv = 1.0f / wsum;

    // ---- broadcast all 8 (idx, w) across the 4-lane group (width-4 shfl) ----
    int   idxk[KNN];
    float wk[KNN];
#pragma unroll
    for (int m = 0; m < 4; ++m) {
        idxk[2 * m]     = __shfl(i2.x, m, 4);
        idxk[2 * m + 1] = __shfl(i2.y, m, 4);
        wk[2 * m]       = __shfl(w0, m, 4);
        wk[2 * m + 1]   = __shfl(w1, m, 4);
    }

    // ---- cooperative row gather: lane j loads chunk j of each row.
    //      One wave instruction now touches only 16 distinct 64-B lines. ----
    const float4* pf4 = (const float4*)points_feat;
    float4 r[KNN];
#pragma unroll
    for (int k = 0; k < KNN; ++k)
        r[k] = pf4[(long long)idxk[k] * 4 + j];

    // lane j accumulates channels 4j..4j+3 of feat (distributed, no reduce)
    float4 f = make_float4(0.f, 0.f, 0.f, 0.f);
#pragma unroll
    for (int k = 0; k < KNN; ++k) {
        f.x = fmaf(wk[k], r[k].x, f.x);
        f.y = fmaf(wk[k], r[k].y, f.y);
        f.z = fmaf(wk[k], r[k].z, f.z);
        f.w = fmaf(wk[k], r[k].w, f.w);
    }

    __syncthreads();   // weights staged

    // ---- head: partial 4-dots per lane, then 4-lane butterfly sum ----
    float pr0 = 0.f, pr1 = 0.f, pr2 = 0.f, ps = 0.f;
    {
        const float fv[4] = {f.x, f.y, f.z, f.w};
#pragma unroll
        for (int m = 0; m < 4; ++m) {
            const int c = 4 * j + m;
            pr0 = fmaf(fv[m], s_wrgb[c * 3 + 0], pr0);
            pr1 = fmaf(fv[m], s_wrgb[c * 3 + 1], pr1);
            pr2 = fmaf(fv[m], s_wrgb[c * 3 + 2], pr2);
            ps  = fmaf(fv[m], s_wsig[c], ps);
        }
    }
    pr0 += __shfl_xor(pr0, 1); pr0 += __shfl_xor(pr0, 2);
    pr1 += __shfl_xor(pr1, 1); pr1 += __shfl_xor(pr1, 2);
    pr2 += __shfl_xor(pr2, 1); pr2 += __shfl_xor(pr2, 2);
    ps  += __shfl_xor(ps, 1);  ps  += __shfl_xor(ps, 2);

    if (j == 0) {
        s_sig[s]     = ps * winv;
        s_rgbv[0][s] = 1.0f / (1.0f + expf(-pr0 * winv));
        s_rgbv[1][s] = 1.0f / (1.0f + expf(-pr1 * winv));
        s_rgbv[2][s] = 1.0f / (1.0f + expf(-pr2 * winv));
    }
    __syncthreads();

    // ---- phase 2: per-ray scan + reductions on first 128 threads ----
    float p = 0.0f, alpha = 0.0f, zv = 0.0f;
    float r0 = 0.0f, r1 = 0.0f, r2 = 0.0f;
    const int lane = t & 63;
    const int wid  = t >> 6;
    if (t < SRS) {
        const long long m = (long long)ray * SRS + t;
        const float del = __builtin_nontemporal_load(delta  + m);
        zv              = __builtin_nontemporal_load(z_vals + m);
        const float sg  = fmaxf(s_sig[t], 0.0f);
        alpha = 1.0f - expf(-sg * del);
        r0 = s_rgbv[0][t]; r1 = s_rgbv[1][t]; r2 = s_rgbv[2][t];

        // inclusive prefix product of (1 - alpha + 1e-10) within wave
        p = 1.0f - alpha + 1e-10f;
#pragma unroll
        for (int off = 1; off < 64; off <<= 1) {
            float v = __shfl_up(p, off, 64);
            if (lane >= off) p *= v;
        }
        if (wid == 0 && lane == 63) s_wavetot = p;
    }
    __syncthreads();

    if (t < SRS) {
        float pm1  = __shfl_up(p, 1, 64);
        float excl = (lane == 0) ? 1.0f : pm1;
        if (wid == 1) excl *= s_wavetot;
        const float wts = alpha * excl;

        float v0 = wts * r0;
        float v1 = wts * r1;
        float v2 = wts * r2;
        float v3 = wts * zv;
        float v4 = wts;
#pragma unroll
        for (int off = 32; off >= 1; off >>= 1) {
            v0 += __shfl_down(v0, off, 64);
            v1 += __shfl_down(v1, off, 64);
            v2 += __shfl_down(v2, off, 64);
            v3 += __shfl_down(v3, off, 64);
            v4 += __shfl_down(v4, off, 64);
        }
        if (lane == 0) {
            s_red[wid][0] = v0;
            s_red[wid][1] = v1;
            s_red[wid][2] = v2;
            s_red[wid][3] = v3;
            s_red[wid][4] = v4;
        }
    }
    __syncthreads();

    if (t == 0) {
        float q0  = s_red[0][0] + s_red[1][0];
        float q1  = s_red[0][1] + s_red[1][1];
        float q2  = s_red[0][2] + s_red[1][2];
        float dep = s_red[0][3] + s_red[1][3];
        float acc = s_red[0][4] + s_red[1][4];
        float bg  = 1.0f - acc;
        float* o = out + (long long)ray * 5;
        o[0] = q0 + bg;
        o[1] = q1 + bg;
        o[2] = q2 + bg;
        o[3] = dep;
        o[4] = acc;
    }
}

extern "C" void kernel_launch(void* const* d_in, const int* in_sizes, int n_in,
                              void* d_out, int out_size, void* d_ws, size_t ws_size,
                              hipStream_t stream) {
    const float* points_feat = (const float*)d_in[0];
    const int*   indices     = (const int*)d_in[1];
    const float* dists       = (const float*)d_in[2];
    const float* w_rgb       = (const float*)d_in[3];
    const float* w_sigma     = (const float*)d_in[4];
    const float* delta       = (const float*)d_in[5];
    const float* z_vals      = (const float*)d_in[6];
    float* out = (float*)d_out;

    pvr_fused_kernel<<<NRAYS, TPB, 0, stream>>>(
        points_feat, indices, dists, w_rgb, w_sigma, delta, z_vals, out);
}